// Round 2
// baseline (99.133 us; speedup 1.0000x reference)
//
#include <hip/hip_runtime.h>
#include <math.h>

// Problem constants
#define BATCH     128
#define MOBJ      64
#define HFULL     112
#define CROP0     28
#define CROPSZ    56            // 84 - 28
#define ROWBLKS   4             // row-groups per batch
#define ROWS_PB   14            // rows per block (56/4)
#define TPB       128
#define HID       64
#define OUTK      36            // 3 * 12
#define INV2S2    0.125f        // 1 / (2 * sigma^2), sigma = 2
#define CULL_R    18            // exp(-18^2/8) ~ 2.5e-18 -> negligible

// ws layout (floats): [0..511]  aux partial per gauss block (b*4 + ry)
//                     [512,513] motion partials (2 waves of the motion block)
#define WS_MOTION 512
#define NBLOCKS   ((BATCH + 1) * ROWBLKS)   // 516 blocks total

// Persistent grid-completion counter. Monotonic across iterations; the block
// observing (old % NBLOCKS) == NBLOCKS-1 is the last of its iteration. No
// per-iteration reset needed; wraps only after ~8.3M iterations.
__device__ unsigned int g_ctr = 0;

// ---------------------------------------------------------------------------
// Single fused kernel: gauss+BCE partials (b<128), motion MLP (b==128,y==0),
// and grid-wide final reduction in the last-arriving block.
// grid = (129, 4), block = 128.
// ---------------------------------------------------------------------------
__global__ __launch_bounds__(TPB) void fused_all(
    const int* __restrict__ goal_pixel,   // [B,2] (col, row)
    const int* __restrict__ obj_list,     // [B,M,2] (col, row)
    const int* __restrict__ obj_num,      // [B]
    const int* __restrict__ road_mask,    // [B,112,112]
    const float* __restrict__ goal_logits,// [B,56,56]
    const float* __restrict__ tpos,       // [B,12,2]
    const float* __restrict__ tyaw,       // [B,12,1]
    const float* __restrict__ w1,         // [2,64]
    const float* __restrict__ b1,         // [64]
    const float* __restrict__ w2,         // [64,36]
    const float* __restrict__ b2,         // [36]
    float* __restrict__ ws,
    float* __restrict__ out)
{
    const int b   = blockIdx.x;
    const int tid = threadIdx.x;

    __shared__ float s_rowf[MOBJ][16];
    __shared__ float s_xo[MOBJ];
    __shared__ float s_ycol[MOBJ];
    __shared__ float s_red[2];
    __shared__ float s_fin[2];
    __shared__ int   s_cnt;
    __shared__ int   s_last;

    if (b == BATCH) {
        // ---------------- motion MLP block (y==0 only) ----------------
        if (blockIdx.y == 0) {
            const int bb = tid;                   // one thread per batch elem
            const float x0 = (float)goal_pixel[bb * 2 + 0];
            const float x1 = (float)goal_pixel[bb * 2 + 1];

            float acc[OUTK];
#pragma unroll
            for (int k = 0; k < OUTK; ++k) acc[k] = b2[k];
            for (int j = 0; j < HID; ++j) {
                float hj = fmaxf(fmaf(x0, w1[j], fmaf(x1, w1[HID + j], b1[j])), 0.0f);
#pragma unroll
                for (int k = 0; k < OUTK; ++k)
                    acc[k] = fmaf(hj, w2[j * OUTK + k], acc[k]);
            }
            float err = 0.0f;
#pragma unroll
            for (int k = 0; k < OUTK; ++k) {
                int t = k / 3, c = k - 3 * t;
                float tg = (c < 2) ? tpos[(bb * 12 + t) * 2 + c] : tyaw[bb * 12 + t];
                float d  = acc[k] - tg;
                err = fmaf(d, d, err);
            }
            err *= (1.0f / (BATCH * OUTK));
            for (int off = 32; off > 0; off >>= 1)
                err += __shfl_down(err, off, 64);
            if ((tid & 63) == 0) ws[WS_MOTION + (tid >> 6)] = err;
        }
        // (b==BATCH, y>0) blocks: no work, fall through to the tail.
    } else {
        // ---------------- gauss + BCE block ----------------
        const int row0 = blockIdx.y * ROWS_PB;    // crop-local first row
        const int rq   = tid / CROPSZ;            // 0,1 active; 2 = idle lanes
        const int w    = tid - rq * CROPSZ;
        const int rlo  = CROP0 + row0;

        const int n = obj_num[b];

        // Prefetch per-pixel globals early so their latency overlaps the
        // compaction + staging phases below.
        float xL = 0.0f, yL = 0.0f;
        float xlog[7];
        int   rmv[7];
        if (rq < 2) {
            xL = (float)goal_pixel[b * 2 + 1];
            yL = (float)goal_pixel[b * 2 + 0];
#pragma unroll
            for (int i = 0; i < 7; ++i) {
                int h = row0 + rq * 7 + i;        // crop-local row
                xlog[i] = goal_logits[(b * CROPSZ + h) * CROPSZ + w];
                rmv[i]  = road_mask[(b * HFULL + CROP0 + h) * HFULL + (CROP0 + w)];
            }
        }

        // ---- cull + compact via wave-0 ballot/prefix (no LDS atomics) ----
        if (tid < 64) {
            int xo = obj_list[(b * MOBJ + tid) * 2 + 1];  // row coord
            int yo = obj_list[(b * MOBJ + tid) * 2 + 0];  // col coord
            bool keep = (tid < n) &&
                        (xo >= rlo - CULL_R) &&
                        (xo <= rlo + ROWS_PB - 1 + CULL_R);
            unsigned long long mk = __ballot(keep);
            if (keep) {
                int idx = (int)__popcll(mk & ((1ull << tid) - 1ull));
                s_xo[idx]   = (float)xo;
                s_ycol[idx] = (float)yo;
            }
            if (tid == 0) s_cnt = (int)__popcll(mk);
        }
        __syncthreads();
        const int nc = s_cnt;

        // Stage per-object row factors (compacted list)
        // s_rowf[m][j]: j in [0,8) -> rows rlo+0..6 (j==7 pad=0)
        //              j in [8,16) -> rows rlo+7..13 (j==15 pad=0)
        for (int i = tid; i < nc * 16; i += TPB) {
            int m  = i >> 4;
            int j  = i & 15;
            int g  = j >> 3;
            int jj = j & 7;
            float v = 0.0f;
            if (jj < 7) {
                float xo = s_xo[m];
                float r  = (float)(rlo + g * 7 + jj);
                float d  = r - xo;
                v = __expf(-d * d * INV2S2);
            }
            s_rowf[m][j] = v;
        }
        __syncthreads();

        float aux = 0.0f;
        if (rq < 2) {
            const float wf = (float)(CROP0 + w);
            const float dC = wf - yL;
            const float gc = __expf(-dC * dC * INV2S2);

            float acc[8];
#pragma unroll
            for (int i = 0; i < 8; ++i) acc[i] = 0.0f;

            const float4* rowp = (const float4*)&s_rowf[0][rq * 8];
            for (int m = 0; m < nc; ++m) {
                float yo = s_ycol[m];
                float d  = wf - yo;
                float cf = __expf(-d * d * INV2S2);
                float4 r0 = rowp[m * 4];       // s_rowf[m][rq*8 .. +3]
                float4 r1 = rowp[m * 4 + 1];   // s_rowf[m][rq*8+4 .. +7]
                acc[0] = fmaf(r0.x, cf, acc[0]);
                acc[1] = fmaf(r0.y, cf, acc[1]);
                acc[2] = fmaf(r0.z, cf, acc[2]);
                acc[3] = fmaf(r0.w, cf, acc[3]);
                acc[4] = fmaf(r1.x, cf, acc[4]);
                acc[5] = fmaf(r1.y, cf, acc[5]);
                acc[6] = fmaf(r1.z, cf, acc[6]);
                acc[7] = fmaf(r1.w, cf, acc[7]);
            }

#pragma unroll
            for (int i = 0; i < 7; ++i) {
                int   gh = rlo + rq * 7 + i;       // full-image row
                float dr = (float)gh - xL;
                float g  = __expf(-dr * dr * INV2S2) * gc;
                float gt = rmv[i] ? (0.5f + 0.5f * g - 0.5f * acc[i]) : 0.0f;
                float x  = xlog[i];
                float t  = __expf(-fabsf(x));
                float sp = fmaxf(x, 0.0f) + __logf(1.0f + t);
                aux += sp - x * gt;
            }
        }

        // Block reduce (2 waves)
        for (int off = 32; off > 0; off >>= 1)
            aux += __shfl_down(aux, off, 64);
        if ((tid & 63) == 0) s_red[tid >> 6] = aux;
        __syncthreads();
        if (tid == 0)
            ws[b * ROWBLKS + blockIdx.y] = s_red[0] + s_red[1];
    }

    // ---- tail: grid-wide completion counter + final reduce in last block ----
    __threadfence();            // release: every thread's ws stores device-visible
    __syncthreads();            // all fences in this block done before the atomic
    if (tid == 0) {
        unsigned int old = atomicAdd(&g_ctr, 1u);
        s_last = ((old % NBLOCKS) == (NBLOCKS - 1)) ? 1 : 0;
    }
    __syncthreads();
    if (s_last) {
        __threadfence();        // acquire: invalidate before reading others' partials
        float a = ws[tid] + ws[tid + 128] + ws[tid + 256] + ws[tid + 384];
        for (int off = 32; off > 0; off >>= 1)
            a += __shfl_down(a, off, 64);
        if ((tid & 63) == 0) s_fin[tid >> 6] = a;
        __syncthreads();
        if (tid == 0) {
            float aux    = s_fin[0] + s_fin[1];
            float motion = ws[WS_MOTION] + ws[WS_MOTION + 1];
            out[0] = aux + motion;
            out[1] = aux;
            out[2] = motion;
        }
    }
}

extern "C" void kernel_launch(void* const* d_in, const int* in_sizes, int n_in,
                              void* d_out, int out_size, void* d_ws, size_t ws_size,
                              hipStream_t stream) {
    const int*   goal_pixel  = (const int*)d_in[0];
    const int*   obj_list    = (const int*)d_in[1];
    const int*   obj_num     = (const int*)d_in[2];
    const int*   road_mask   = (const int*)d_in[3];
    const float* goal_logits = (const float*)d_in[4];
    const float* target_pos  = (const float*)d_in[5];
    const float* target_yaw  = (const float*)d_in[6];
    const float* w1          = (const float*)d_in[7];
    const float* b1          = (const float*)d_in[8];
    const float* w2          = (const float*)d_in[9];
    const float* b2          = (const float*)d_in[10];
    float* out = (float*)d_out;
    float* ws  = (float*)d_ws;

    dim3 grid1(BATCH + 1, ROWBLKS);
    fused_all<<<grid1, TPB, 0, stream>>>(
        goal_pixel, obj_list, obj_num, road_mask, goal_logits,
        target_pos, target_yaw, w1, b1, w2, b2, ws, out);
}

// Round 3
// 89.555 us; speedup vs baseline: 1.1069x; 1.1069x over previous
//
#include <hip/hip_runtime.h>
#include <math.h>

// Problem constants
#define BATCH     128
#define MOBJ      64
#define HFULL     112
#define CROP0     28
#define CROPSZ    56            // 84 - 28
#define ROWBLKS   4             // row-groups per batch
#define ROWS_PB   14            // rows per block (56/4)
#define TPB       128
#define HID       64
#define OUTK      36            // 3 * 12
#define INV2S2    0.125f        // 1 / (2 * sigma^2), sigma = 2
#define CULL_R    18            // exp(-18^2/8) ~ 2.5e-18 -> negligible

// ws layout (floats): [0..511]  aux partial per gauss block (b*4 + ry)
//                     [512,513] motion partials (2 waves of the motion block)
#define WS_MOTION 512

// ---------------------------------------------------------------------------
// Kernel 1: fused gauss+BCE partials (blocks b<128) and motion MLP (b==128).
// grid = (129, 4), block = 128.
// ---------------------------------------------------------------------------
__global__ __launch_bounds__(TPB) void fused_partials(
    const int* __restrict__ goal_pixel,   // [B,2] (col, row)
    const int* __restrict__ obj_list,     // [B,M,2] (col, row)
    const int* __restrict__ obj_num,      // [B]
    const int* __restrict__ road_mask,    // [B,112,112]
    const float* __restrict__ goal_logits,// [B,56,56]
    const float* __restrict__ tpos,       // [B,12,2]
    const float* __restrict__ tyaw,       // [B,12,1]
    const float* __restrict__ w1,         // [2,64]
    const float* __restrict__ b1,         // [64]
    const float* __restrict__ w2,         // [64,36]
    const float* __restrict__ b2,         // [36]
    float* __restrict__ ws)
{
    const int b   = blockIdx.x;
    const int tid = threadIdx.x;

    // ---------------- motion MLP block ----------------
    if (b == BATCH) {
        if (blockIdx.y != 0) return;
        const int bb = tid;                       // one thread per batch elem
        const float x0 = (float)goal_pixel[bb * 2 + 0];
        const float x1 = (float)goal_pixel[bb * 2 + 1];

        float acc[OUTK];
#pragma unroll
        for (int k = 0; k < OUTK; ++k) acc[k] = b2[k];
        for (int j = 0; j < HID; ++j) {
            float hj = fmaxf(fmaf(x0, w1[j], fmaf(x1, w1[HID + j], b1[j])), 0.0f);
#pragma unroll
            for (int k = 0; k < OUTK; ++k)
                acc[k] = fmaf(hj, w2[j * OUTK + k], acc[k]);
        }
        float err = 0.0f;
#pragma unroll
        for (int k = 0; k < OUTK; ++k) {
            int t = k / 3, c = k - 3 * t;
            float tg = (c < 2) ? tpos[(bb * 12 + t) * 2 + c] : tyaw[bb * 12 + t];
            float d  = acc[k] - tg;
            err = fmaf(d, d, err);
        }
        err *= (1.0f / (BATCH * OUTK));
        for (int off = 32; off > 0; off >>= 1)
            err += __shfl_down(err, off, 64);
        if ((tid & 63) == 0) ws[WS_MOTION + (tid >> 6)] = err;
        return;
    }

    // ---------------- gauss + BCE block ----------------
    const int row0 = blockIdx.y * ROWS_PB;        // crop-local first row
    const int rq   = tid / CROPSZ;                // 0,1 active; 2 = idle lanes
    const int w    = tid - rq * CROPSZ;
    const int rlo  = CROP0 + row0;

    __shared__ float s_rowf[MOBJ][16];
    __shared__ float s_xo[MOBJ];
    __shared__ float s_ycol[MOBJ];
    __shared__ float s_red[2];
    __shared__ int   s_cnt;

    const int n = obj_num[b];

    // Prefetch per-pixel globals early so their latency overlaps the
    // compaction + staging phases below.
    float xL = 0.0f, yL = 0.0f;
    float xlog[7];
    int   rmv[7];
    if (rq < 2) {
        xL = (float)goal_pixel[b * 2 + 1];
        yL = (float)goal_pixel[b * 2 + 0];
#pragma unroll
        for (int i = 0; i < 7; ++i) {
            int h = row0 + rq * 7 + i;            // crop-local row
            xlog[i] = goal_logits[(b * CROPSZ + h) * CROPSZ + w];
            rmv[i]  = road_mask[(b * HFULL + CROP0 + h) * HFULL + (CROP0 + w)];
        }
    }

    // ---- cull + compact via wave-0 ballot/prefix (no LDS atomics) ----
    if (tid < 64) {
        int xo = obj_list[(b * MOBJ + tid) * 2 + 1];  // row coord
        int yo = obj_list[(b * MOBJ + tid) * 2 + 0];  // col coord
        bool keep = (tid < n) &&
                    (xo >= rlo - CULL_R) &&
                    (xo <= rlo + ROWS_PB - 1 + CULL_R);
        unsigned long long mk = __ballot(keep);
        if (keep) {
            int idx = (int)__popcll(mk & ((1ull << tid) - 1ull));
            s_xo[idx]   = (float)xo;
            s_ycol[idx] = (float)yo;
        }
        if (tid == 0) s_cnt = (int)__popcll(mk);
    }
    __syncthreads();
    const int nc = s_cnt;

    // Stage per-object row factors (compacted list)
    // s_rowf[m][j]: j in [0,8) -> rows rlo+0..6 (j==7 pad=0)
    //              j in [8,16) -> rows rlo+7..13 (j==15 pad=0)
    for (int i = tid; i < nc * 16; i += TPB) {
        int m  = i >> 4;
        int j  = i & 15;
        int g  = j >> 3;
        int jj = j & 7;
        float v = 0.0f;
        if (jj < 7) {
            float xo = s_xo[m];
            float r  = (float)(rlo + g * 7 + jj);
            float d  = r - xo;
            v = __expf(-d * d * INV2S2);
        }
        s_rowf[m][j] = v;
    }
    __syncthreads();

    float aux = 0.0f;
    if (rq < 2) {
        const float wf = (float)(CROP0 + w);
        const float dC = wf - yL;
        const float gc = __expf(-dC * dC * INV2S2);

        float acc[8];
#pragma unroll
        for (int i = 0; i < 8; ++i) acc[i] = 0.0f;

        const float4* rowp = (const float4*)&s_rowf[0][rq * 8];
        for (int m = 0; m < nc; ++m) {
            float yo = s_ycol[m];
            float d  = wf - yo;
            float cf = __expf(-d * d * INV2S2);
            float4 r0 = rowp[m * 4];       // s_rowf[m][rq*8 .. +3]
            float4 r1 = rowp[m * 4 + 1];   // s_rowf[m][rq*8+4 .. +7]
            acc[0] = fmaf(r0.x, cf, acc[0]);
            acc[1] = fmaf(r0.y, cf, acc[1]);
            acc[2] = fmaf(r0.z, cf, acc[2]);
            acc[3] = fmaf(r0.w, cf, acc[3]);
            acc[4] = fmaf(r1.x, cf, acc[4]);
            acc[5] = fmaf(r1.y, cf, acc[5]);
            acc[6] = fmaf(r1.z, cf, acc[6]);
            acc[7] = fmaf(r1.w, cf, acc[7]);
        }

#pragma unroll
        for (int i = 0; i < 7; ++i) {
            int   gh = rlo + rq * 7 + i;       // full-image row
            float dr = (float)gh - xL;
            float g  = __expf(-dr * dr * INV2S2) * gc;
            float gt = rmv[i] ? (0.5f + 0.5f * g - 0.5f * acc[i]) : 0.0f;
            float x  = xlog[i];
            float t  = __expf(-fabsf(x));
            float sp = fmaxf(x, 0.0f) + __logf(1.0f + t);
            aux += sp - x * gt;
        }
    }

    // Block reduce (2 waves)
    for (int off = 32; off > 0; off >>= 1)
        aux += __shfl_down(aux, off, 64);
    if ((tid & 63) == 0) s_red[tid >> 6] = aux;
    __syncthreads();
    if (tid == 0)
        ws[b * ROWBLKS + blockIdx.y] = s_red[0] + s_red[1];
}

// ---------------------------------------------------------------------------
// Kernel 2: reduce 512 aux partials + 2 motion partials -> out[0..2].
// 1 block, 256 threads.
// ---------------------------------------------------------------------------
__global__ __launch_bounds__(256) void reduce_out(
    const float* __restrict__ ws, float* __restrict__ out)
{
    const int t = threadIdx.x;
    float a = ws[t] + ws[t + 256];
    for (int off = 32; off > 0; off >>= 1)
        a += __shfl_down(a, off, 64);
    __shared__ float s[4];
    if ((t & 63) == 0) s[t >> 6] = a;
    __syncthreads();
    if (t == 0) {
        float aux    = s[0] + s[1] + s[2] + s[3];
        float motion = ws[WS_MOTION] + ws[WS_MOTION + 1];
        out[0] = aux + motion;
        out[1] = aux;
        out[2] = motion;
    }
}

extern "C" void kernel_launch(void* const* d_in, const int* in_sizes, int n_in,
                              void* d_out, int out_size, void* d_ws, size_t ws_size,
                              hipStream_t stream) {
    const int*   goal_pixel  = (const int*)d_in[0];
    const int*   obj_list    = (const int*)d_in[1];
    const int*   obj_num     = (const int*)d_in[2];
    const int*   road_mask   = (const int*)d_in[3];
    const float* goal_logits = (const float*)d_in[4];
    const float* target_pos  = (const float*)d_in[5];
    const float* target_yaw  = (const float*)d_in[6];
    const float* w1          = (const float*)d_in[7];
    const float* b1          = (const float*)d_in[8];
    const float* w2          = (const float*)d_in[9];
    const float* b2          = (const float*)d_in[10];
    float* out = (float*)d_out;
    float* ws  = (float*)d_ws;

    dim3 grid1(BATCH + 1, ROWBLKS);
    fused_partials<<<grid1, TPB, 0, stream>>>(
        goal_pixel, obj_list, obj_num, road_mask, goal_logits,
        target_pos, target_yaw, w1, b1, w2, b2, ws);

    reduce_out<<<1, 256, 0, stream>>>(ws, out);
}